// Round 16
// baseline (226.490 us; speedup 1.0000x reference)
//
#include <hip/hip_runtime.h>

#define NCLUSTER 512
#define NC 3
#define HW 65536
#define GRID1 16
#define NCELL (GRID1*GRID1*GRID1)     // 4096
#define RANGE 4.0f
#define INV_H 2.0f
#define EPS 1e-4f
#define TBMARGIN 1e-2f

// ws layout (bytes):
//      0: float4 sortedC[512]          (8192)
//   8192: u16   origId[512]            (1024)
//   9216: u16   cellClusterStart[4097] (8194, pad to 17920)
//  17920: u32   H[4096]  hist->cursor  (16384, pad to 34816)
//  34816: u32   bucketList[262144]     (1048576) -> total 1083392
#define WS_OID    8192
#define WS_CST    9216
#define WS_H      17920
#define WS_BUCKET 34816
#define WS_NEED   (WS_BUCKET + 262144*4)

__device__ __forceinline__ int cell_of(float x0, float x1, float x2) {
    int ci = min(max((int)floorf((x0+RANGE)*INV_H), 0), GRID1-1);
    int cj = min(max((int)floorf((x1+RANGE)*INV_H), 0), GRID1-1);
    int ck = min(max((int)floorf((x2+RANGE)*INV_H), 0), GRID1-1);
    return (ci*GRID1 + cj)*GRID1 + ck;
}

// ---- cluster CSR builder (R15, validated absmax 0) ----
__global__ __launch_bounds__(512) void kmeans_build(
    const float* __restrict__ C, void* __restrict__ ws)
{
    float4* sortedC = (float4*)ws;
    ushort* origId  = (ushort*)((char*)ws + WS_OID);
    ushort* cellSt  = (ushort*)((char*)ws + WS_CST);

    __shared__ int cnt[NCELL];
    __shared__ int start[NCELL];
    __shared__ int part[512];
    const int t = threadIdx.x;
#pragma unroll
    for (int i = 0; i < NCELL/512; ++i) cnt[t + i*512] = 0;
    __syncthreads();

    int mycell = 0; float c0 = 0, c1 = 0, c2 = 0;
    if (t < NCLUSTER) {
        c0 = C[t*NC+0]; c1 = C[t*NC+1]; c2 = C[t*NC+2];
        mycell = cell_of(c0, c1, c2);
        atomicAdd(&cnt[mycell], 1);
    }
    __syncthreads();
    int s = 0;
#pragma unroll
    for (int i = 0; i < 8; ++i) s += cnt[t*8+i];
    part[t] = s;
    __syncthreads();
    for (int d = 1; d < 512; d <<= 1) {
        int v = (t >= d) ? part[t-d] : 0;
        __syncthreads();
        part[t] += v;
        __syncthreads();
    }
    int run = (t == 0) ? 0 : part[t-1];
#pragma unroll
    for (int i = 0; i < 8; ++i) { start[t*8+i] = run; run += cnt[t*8+i]; }
    __syncthreads();
#pragma unroll
    for (int i = 0; i < 8; ++i) cellSt[t*8+i] = (ushort)start[t*8+i];
    if (t == 0) cellSt[NCELL] = (ushort)NCLUSTER;
#pragma unroll
    for (int i = 0; i < NCELL/512; ++i) cnt[t + i*512] = 0;
    __syncthreads();
    if (t < NCLUSTER) {
        int r = atomicAdd(&cnt[mycell], 1);
        int pos = start[mycell] + r;
        double d0 = c0, d1 = c1, d2 = c2;
        sortedC[pos] = make_float4(c0, c1, c2,
                                   (float)(0.5*(d0*d0 + d1*d1 + d2*d2)));
        origId[pos] = (ushort)t;
    }
}

// ---- pixel histogram (H zeroed by memset before this) ----
__global__ __launch_bounds__(512) void px_hist(
    const float* __restrict__ x, void* __restrict__ ws)
{
    uint* H = (uint*)((char*)ws + WS_H);
    int px = blockIdx.x * 512 + threadIdx.x;
    int p = px & (HW-1);
    const float* xb = x + (size_t)(px >> 16) * NC * HW;
    atomicAdd(&H[cell_of(xb[p], xb[p+HW], xb[p+2*HW])], 1u);
}

// ---- scan: H (counts) -> H (exclusive starts; becomes scatter cursor) ----
__global__ __launch_bounds__(512) void px_scan(void* __restrict__ ws)
{
    uint* H = (uint*)((char*)ws + WS_H);
    __shared__ uint loc[NCELL];
    __shared__ uint part[512];
    const int t = threadIdx.x;
#pragma unroll
    for (int i = 0; i < 8; ++i) loc[t*8+i] = H[t*8+i];
    __syncthreads();
    uint s = 0;
#pragma unroll
    for (int i = 0; i < 8; ++i) s += loc[t*8+i];
    part[t] = s;
    __syncthreads();
    for (int d = 1; d < 512; d <<= 1) {
        uint v = (t >= d) ? part[t-d] : 0;
        __syncthreads();
        part[t] += v;
        __syncthreads();
    }
    uint run = (t == 0) ? 0 : part[t-1];
#pragma unroll
    for (int i = 0; i < 8; ++i) { uint c = loc[t*8+i]; H[t*8+i] = run; run += c; }
}

// ---- scatter pixel ids into cell buckets ----
__global__ __launch_bounds__(512) void px_scatter(
    const float* __restrict__ x, void* __restrict__ ws)
{
    uint* H  = (uint*)((char*)ws + WS_H);
    uint* BL = (uint*)((char*)ws + WS_BUCKET);
    int px = blockIdx.x * 512 + threadIdx.x;
    int p = px & (HW-1);
    const float* xb = x + (size_t)(px >> 16) * NC * HW;
    uint pos = atomicAdd(&H[cell_of(xb[p], xb[p+HW], xb[p+2*HW])], 1u);
    BL[pos] = (uint)px;
}

// ---- assign: bucketed pixels -> wave-uniform candidate scan + 3-tier cert ----
#define ABLOCK 256
#define ANW 4
__global__ __launch_bounds__(ABLOCK) void kmeans_assign(
    const float* __restrict__ x, const void* __restrict__ ws,
    int* __restrict__ out)
{
    const float4* g_sc  = (const float4*)ws;
    const uint*   g_oid = (const uint*)((const char*)ws + WS_OID);
    const uint*   g_cs  = (const uint*)((const char*)ws + WS_CST);
    const uint*   BL    = (const uint*)((const char*)ws + WS_BUCKET);

    __shared__ float4 lcS[NCLUSTER];
    __shared__ ushort oid[NCLUSTER];
    __shared__ ushort cst[NCELL+2];
    __shared__ int qpx[ABLOCK], q2[ABLOCK];
    __shared__ int qcnt, q2cnt;

    const int tid = threadIdx.x;
    if (tid == 0) { qcnt = 0; q2cnt = 0; }
#pragma unroll
    for (int i = 0; i < 2; ++i) lcS[tid + i*ABLOCK] = g_sc[tid + i*ABLOCK];
    ((uint*)oid)[tid] = g_oid[tid];              // 256 u32 = 512 u16
    for (int k = tid; k < 2049; k += ABLOCK) ((uint*)cst)[k] = g_cs[k];

    const int slot = blockIdx.x * ABLOCK + tid;
    const int gpx = (int)BL[slot];
    const int p = gpx & (HW-1);
    const float* xb = x + (size_t)(gpx >> 16) * NC * HW;
    float x0 = xb[p], x1 = xb[p+HW], x2 = xb[p+2*HW];
    float S = __builtin_fmaf(x0, x0, __builtin_fmaf(x1, x1, x2*x2));
    __syncthreads();

    // phase 1: 27-cell scan; lanes in a wave share a cell (bucketed) -> uniform
    float b1 = 1e30f, b2 = 1e30f;
    int idq = 0;
    bool oob = (fabsf(x0) >= 3.999f) | (fabsf(x1) >= 3.999f) | (fabsf(x2) >= 3.999f);
    bool ok = false;
    if (!oob) {
        int ci = (int)floorf((x0+RANGE)*INV_H);
        int cj = (int)floorf((x1+RANGE)*INV_H);
        int ck = (int)floorf((x2+RANGE)*INV_H);
#pragma unroll
        for (int dx = -1; dx <= 1; ++dx) {
#pragma unroll
            for (int dy = -1; dy <= 1; ++dy) {
#pragma unroll
                for (int dz = -1; dz <= 1; ++dz) {
                    int ii = ci+dx, jj = cj+dy, kk = ck+dz;
                    if ((unsigned)ii < GRID1 && (unsigned)jj < GRID1 &&
                        (unsigned)kk < GRID1) {
                        int cell = (ii*GRID1 + jj)*GRID1 + kk;
                        int qs = cst[cell], qe = cst[cell+1];
                        for (int q = qs; q < qe; ++q) {
                            float4 c = lcS[q];
                            float t = __builtin_fmaf(-x0, c.x, c.w);
                            t = __builtin_fmaf(-x1, c.y, t);
                            t = __builtin_fmaf(-x2, c.z, t);
                            bool lt = t < b1;
                            b2 = __builtin_amdgcn_fmed3f(t, b1, b2);
                            idq = lt ? q : idq;
                            b1 = fminf(t, b1);
                        }
                    }
                }
            }
        }
        float tb = 0.5f*(0.25f - S) - TBMARGIN;   // unscanned: t >= (0.25-S)/2
        ok = (b2 - b1 >= EPS) && (tb >= b1 + EPS);
    }
    if (ok) out[gpx] = (int)oid[idq];
    else qpx[atomicAdd(&qcnt, 1)] = gpx;
    __syncthreads();

    // phase 2: full-512 certified fp32, one queued px per wave
    const int w = tid >> 6, l = tid & 63;
    const int n1 = qcnt;
    for (int e = w; e < n1; e += ANW) {
        const int gq = qpx[e];
        const int pq = gq & (HW-1);
        const float* xq = x + (size_t)(gq >> 16) * NC * HW;
        float y0 = xq[pq], y1 = xq[pq+HW], y2 = xq[pq+2*HW];
        float pb1 = 1e30f, pb2 = 1e30f;
        int pid = 0x7fffffff;
#pragma unroll
        for (int j = 0; j < NCLUSTER/64; ++j) {
            int q = j*64 + l;
            float4 c = lcS[q];
            int kid = oid[q];
            float tt = __builtin_fmaf(-y0, c.x, c.w);
            tt = __builtin_fmaf(-y1, c.y, tt);
            tt = __builtin_fmaf(-y2, c.z, tt);
            bool bet = (tt < pb1) || (tt == pb1 && kid < pid);
            pb2 = __builtin_amdgcn_fmed3f(tt, pb1, pb2);
            pid = bet ? kid : pid;
            pb1 = fminf(tt, pb1);
        }
#pragma unroll
        for (int m = 1; m < 64; m <<= 1) {
            float ob1 = __shfl_xor(pb1, m, 64);
            float ob2 = __shfl_xor(pb2, m, 64);
            int opid  = __shfl_xor(pid, m, 64);
            pb2 = fminf(fminf(pb2, ob2), fmaxf(pb1, ob1));
            bool take = (ob1 < pb1) || (ob1 == pb1 && opid < pid);
            pid = take ? opid : pid;
            pb1 = fminf(pb1, ob1);
        }
        if (pb2 - pb1 >= EPS) {
            if (l == 0) out[gq] = pid;
        } else {
            if (l == 0) q2[atomicAdd(&q2cnt, 1)] = gq;
        }
    }
    __syncthreads();

    // phase 3: exact fp64 resolve (validated absmax 0), smallest-k ties
    const int n2 = q2cnt;
    for (int e = w; e < n2; e += ANW) {
        const int gq = q2[e];
        const int pq = gq & (HW-1);
        const float* xq = x + (size_t)(gq >> 16) * NC * HW;
        double X0 = xq[pq], X1 = xq[pq+HW], X2 = xq[pq+2*HW];
        double bd = 1e300;
        int bi = 0x7fffffff;
#pragma unroll
        for (int j = 0; j < NCLUSTER/64; ++j) {
            int q = j*64 + l;
            float4 c = lcS[q];
            int kid = oid[q];
            double d0 = X0 - (double)c.x;
            double d1 = X1 - (double)c.y;
            double d2 = X2 - (double)c.z;
            double d = d0*d0 + d1*d1 + d2*d2;
            if (d < bd || (d == bd && kid < bi)) { bd = d; bi = kid; }
        }
#pragma unroll
        for (int m = 1; m < 64; m <<= 1) {
            double od = __shfl_xor(bd, m, 64);
            int oi = __shfl_xor(bi, m, 64);
            bool take = (od < bd) || (od == bd && oi < bi);
            bd = take ? od : bd;
            bi = take ? oi : bi;
        }
        if (l == 0) out[gq] = bi;
    }
}

// ---- R12 fallback (validated 32.4 us) for small ws ----
#define FBLOCK 512
#define FNW 8
#define FKSUB 64
#define FPPT 4
#define FPXB 256
__global__ __launch_bounds__(FBLOCK, 8) void kmeans_assign_flat(
    const float* __restrict__ x, const float* __restrict__ C,
    int* __restrict__ out)
{
    __shared__ float4 lc[NCLUSTER];
    __shared__ float  rb1[FNW][FPXB];
    __shared__ float  rb2[FNW][FPXB];
    __shared__ int    ridx[FNW][FPXB];
    __shared__ int    qpx[FPXB];
    __shared__ int    qcnt;

    const int w = threadIdx.x >> 6;
    const int l = threadIdx.x & 63;
    const int B0 = blockIdx.x * FPXB;
    const int pB = B0 & (HW - 1);
    const float* xb = x + (size_t)(B0 >> 16) * NC * HW;

    float x0[FPPT], x1[FPPT], x2[FPPT];
#pragma unroll
    for (int i = 0; i < FPPT; ++i) {
        int p = pB + l + i * 64;
        x0[i] = xb[p]; x1[i] = xb[p + HW]; x2[i] = xb[p + 2 * HW];
    }
    if (threadIdx.x == 0) qcnt = 0;
    {
        int k = threadIdx.x;
        double c0 = C[k*NC+0], c1 = C[k*NC+1], c2 = C[k*NC+2];
        lc[k] = make_float4((float)c0, (float)c1, (float)c2,
                            (float)(0.5*(c0*c0 + c1*c1 + c2*c2)));
    }
    __syncthreads();
    float b1[FPPT], b2[FPPT]; int id[FPPT];
#pragma unroll
    for (int i = 0; i < FPPT; ++i) { b1[i] = 1e30f; b2[i] = 1e30f; id[i] = 0; }
    const int k0 = w * FKSUB;
#pragma unroll 4
    for (int k = 0; k < FKSUB; ++k) {
        float4 c = lc[k0 + k];
#pragma unroll
        for (int i = 0; i < FPPT; ++i) {
            float t = __builtin_fmaf(-x0[i], c.x, c.w);
            t = __builtin_fmaf(-x1[i], c.y, t);
            t = __builtin_fmaf(-x2[i], c.z, t);
            bool lt = t < b1[i];
            b2[i] = __builtin_amdgcn_fmed3f(t, b1[i], b2[i]);
            id[i] = lt ? (k0 + k) : id[i];
            b1[i] = fminf(t, b1[i]);
        }
    }
#pragma unroll
    for (int i = 0; i < FPPT; ++i) {
        rb1[w][l + i*64] = b1[i]; rb2[w][l + i*64] = b2[i]; ridx[w][l + i*64] = id[i];
    }
    __syncthreads();
    if (threadIdx.x < FPXB) {
        const int t = threadIdx.x;
        float g1m = rb1[0][t], g2m = rb2[0][t]; int gi = ridx[0][t];
#pragma unroll
        for (int ww = 1; ww < FNW; ++ww) {
            float a1 = rb1[ww][t], a2 = rb2[ww][t]; int ai = ridx[ww][t];
            bool lt = a1 < g1m;
            g2m = lt ? fminf(g1m, a2) : fminf(g2m, a1);
            gi = lt ? ai : gi;
            g1m = fminf(g1m, a1);
        }
        if (g2m - g1m < EPS) qpx[atomicAdd(&qcnt, 1)] = t;
        else out[B0 + t] = gi;
    }
    __syncthreads();
    const int n = qcnt;
    for (int e = w; e < n; e += FNW) {
        const int t = qpx[e];
        const int p = pB + t;
        double X0 = xb[p], X1 = xb[p+HW], X2 = xb[p+2*HW];
        double bd = 1e300; int bi = 0;
#pragma unroll
        for (int j = 0; j < NCLUSTER/64; ++j) {
            int k = j*64 + l;
            float4 c = lc[k];
            double d0 = X0 - (double)c.x, d1 = X1 - (double)c.y, d2 = X2 - (double)c.z;
            double d = d0*d0 + d1*d1 + d2*d2;
            if (d < bd) { bd = d; bi = k; }
        }
#pragma unroll
        for (int m = 1; m < 64; m <<= 1) {
            double od = __shfl_xor(bd, m, 64);
            int oi = __shfl_xor(bi, m, 64);
            bool take = (od < bd) || (od == bd && oi < bi);
            bd = take ? od : bd; bi = take ? oi : bi;
        }
        if (l == 0) out[B0 + t] = bi;
    }
}

extern "C" void kernel_launch(void* const* d_in, const int* in_sizes, int n_in,
                              void* d_out, int out_size, void* d_ws, size_t ws_size,
                              hipStream_t stream) {
    const float* x = (const float*)d_in[0];
    const float* C = (const float*)d_in[1];
    int* out = (int*)d_out;
    int total = out_size;              // 262144

    if (ws_size < (size_t)WS_NEED) {   // deterministic fallback: R12 flat scan
        kmeans_assign_flat<<<total / FPXB, FBLOCK, 0, stream>>>(x, C, out);
        return;
    }

    hipMemsetAsync((char*)d_ws + WS_H, 0, NCELL * sizeof(uint), stream);
    kmeans_build<<<1, 512, 0, stream>>>(C, d_ws);
    px_hist   <<<total / 512, 512, 0, stream>>>(x, d_ws);
    px_scan   <<<1, 512, 0, stream>>>(d_ws);
    px_scatter<<<total / 512, 512, 0, stream>>>(x, d_ws);
    kmeans_assign<<<total / ABLOCK, ABLOCK, 0, stream>>>(x, d_ws, out);
}